// Round 3
// baseline (222.814 us; speedup 1.0000x reference)
//
#include <hip/hip_runtime.h>
#include <hip/hip_bf16.h>
#include <hip/hip_fp16.h>

// Problem: B=4096, D=1024, H=8192, O=1000
//   winners[b] = argmin_h ||x_b - k_h||  (== argmax dot, k rows unit-norm)
//   output[b,o] = G[o, winners[b]]
// Pipeline (3 dispatches; measured fixed replay overhead ~75 us):
//   1) cvt: fp32 -> fp8(e4m3) for x,kw (4 rows/block; 8B-half swap for rows
//      with bit3 set = third LDS swizzle bit) + parallel G->Gt transpose
//   2) gemm_top2: fp8 MFMA scores (16x16x32_fp8_fp8). Block 256x128, BK=64,
//      4 waves, 128x64 wave-tile (acc[8][4] AGPRs). TRIPLE-buffered LDS,
//      counted vmcnt(6) (never 0 in loop), ONE raw s_barrier per K-iter:
//      STAGE(t+2) targets buf[(t+2)%3] which holds tile t-1, whose reads
//      completed before this iter's lgkmcnt(0)+barrier -> no second barrier.
//      3-bit LDS swizzle (16B chunk ^ (row>>1)&3, 8B half ^ (row>>3)&1) makes
//      ds_read_b64 bank-pair mapping bijective per quarter-wave -> conflict-free.
//      Top-2 packed keys per (row, 64-col half) -> uint4 per (row, 128-tile).
//   3) select: wave-per-row exact fp64 refinement (margin 0.35 >> fp8 dot err
//      ~0.05) + fused coalesced gather.

#define BB 4096
#define DD 1024
#define HH 8192
#define OO 1000

#define BM 256
#define BN 128
#define BK 64          // bytes == elements (fp8)
#define NTILES (HH / BN)   // 64
#define SA_TILE (BM * BK)  // 16384
#define SB_TILE (BN * BK)  // 8192

typedef _Float16 f16;
typedef float f32x4 __attribute__((ext_vector_type(4)));

typedef __attribute__((address_space(3))) uint32_t lds_u32_t;
typedef __attribute__((address_space(1))) uint32_t glb_u32_t;

// ---- packed key: monotone(float) with low 7 bits = tile-local column ----
__device__ __forceinline__ uint32_t packkey(float v, int col) {
  uint32_t u = __float_as_uint(v);
  uint32_t mask = (uint32_t)((int32_t)u >> 31) | 0x80000000u;
  u ^= mask;                       // monotone: bigger float -> bigger uint
  return (u & 0xFFFFFF80u) | (uint32_t)col;
}
__device__ __forceinline__ float unpackval(uint32_t k) {
  uint32_t u = k & 0xFFFFFF80u;
  uint32_t mask = (k & 0x80000000u) ? 0x80000000u : 0xFFFFFFFFu;
  return __uint_as_float(u ^ mask);
}
__device__ __forceinline__ void kmerge(uint32_t& k1, uint32_t& k2,
                                       uint32_t o1, uint32_t o2) {
  uint32_t mn = min(k1, o1);
  uint32_t alt = (k1 > o1) ? k2 : o2;
  k1 = max(k1, o1);
  k2 = max(mn, alt);
}

// -------- cvt: fp32 -> fp8 e4m3 (4 rows/block) + parallel transpose ---------
// blocks [0, 3072): 4 rows each of x (rows 0..BB-1) then kw (rows BB..BB+HH-1)
//   NOTE: 4B-word index is XOR'd with ((r>>3)&1)<<1 -> swaps the two 8B halves
//   of each 16B chunk for rows 8..15 mod 16. This is the 3rd LDS-swizzle bit;
//   gemm's reader undoes it, so logical data is unchanged.
// blocks [3072, 3072+2048): 4 parallel 32x32 transpose tiles of G -> Gt
__global__ __launch_bounds__(256) void cvt_kernel(
    const float* __restrict__ x, const float* __restrict__ kw,
    uint8_t* __restrict__ xq, uint8_t* __restrict__ kq,
    const float* __restrict__ G, float* __restrict__ Gt) {
  const int tid = threadIdx.x;
  const int blk = blockIdx.x;
  __shared__ float tile[32][33];
  if (blk < (BB + HH) / 4) {
#pragma unroll
    for (int i = 0; i < 4; ++i) {
      int r = blk * 4 + i;
      const float* src = (r < BB) ? (x + (size_t)r * DD)
                                  : (kw + (size_t)(r - BB) * DD);
      uint8_t* dst = (r < BB) ? (xq + (size_t)r * DD)
                              : (kq + (size_t)(r - BB) * DD);
      float4 v = ((const float4*)src)[tid];
      int p = 0;
      p = __builtin_amdgcn_cvt_pk_fp8_f32(v.x, v.y, p, false);  // bytes 0,1
      p = __builtin_amdgcn_cvt_pk_fp8_f32(v.z, v.w, p, true);   // bytes 2,3
      int wi = tid ^ (((r >> 3) & 1) << 1);   // 8B-half swap for row bit3
      ((int*)dst)[wi] = p;
    }
  } else {
    if (Gt == nullptr) return;
    const int tb = blk - (BB + HH) / 4;
    const int tx = tid & 31;
    const int ty = tid >> 5;  // 0..7
#pragma unroll 1
    for (int j4 = 0; j4 < 4; ++j4) {
      int tile_id = tb * 4 + j4;       // 0..8191
      int h0 = (tile_id >> 5) * 32;
      int o0 = (tile_id & 31) * 32;
      __syncthreads();
#pragma unroll
      for (int j = 0; j < 4; ++j) {
        int o = o0 + ty + j * 8;
        if (o < OO) tile[ty + j * 8][tx] = G[(size_t)o * HH + h0 + tx];
      }
      __syncthreads();
#pragma unroll
      for (int j = 0; j < 4; ++j) {
        int o = o0 + tx;
        int h = h0 + ty + j * 8;
        if (o < OO) Gt[(size_t)h * OO + o] = tile[tx][ty + j * 8];
      }
    }
  }
}

// ---------------- GEMM (fp8 scores) + top-2 keys per half-tile --------------
// A = xq [B][D] fp8 (8B-half pre-swizzled), Bt = kq [H][D] fp8 (NT, same).
// Block: 256x128 C-tile, BK=64, 16 K-iters, triple-buffered LDS pipeline.
// Per iter: {vmcnt(6) lgkmcnt(0); s_barrier; STAGE(t+2); 24 ds_read_b64 +
// 64 MFMA (setprio 1)}. Loads for 2 tiles always in flight across barriers.
__global__ __launch_bounds__(256, 2) void gemm_top2(
    const uint8_t* __restrict__ A, const uint8_t* __restrict__ Bt,
    uint4* __restrict__ pk) {
  __shared__ __align__(16) uint8_t sA[3][SA_TILE];  // 48 KB
  __shared__ __align__(16) uint8_t sB[3][SB_TILE];  // 24 KB
  __shared__ uint2 mk[BM][2];                       // 4 KB

  const int tid = threadIdx.x;
  const int w = tid >> 6;       // wave 0..3
  const int L = tid & 63;       // lane

  // XCD-aware bijective remap: grid 64x16 = 1024 blocks = 8 XCD * 128.
  // XCD c (= linear bid & 7) owns n-tiles [8c, 8c+8) across all m.
  const int bid = blockIdx.y * gridDim.x + blockIdx.x;
  const int c8 = bid & 7;
  const int tt = bid >> 3;           // 0..127
  const int nx = c8 * 8 + (tt & 7);  // 0..63
  const int my = tt >> 3;            // 0..15
  const int m0 = my * BM;
  const int n0 = nx * BN;

  const int wr = w >> 1;  // 0,1: row half (128 rows)
  const int wc = w & 1;   // 0,1: col half (64 cols)

  f32x4 acc[8][4];
#pragma unroll
  for (int i = 0; i < 8; ++i)
#pragma unroll
    for (int j = 0; j < 4; ++j) {
      acc[i][j][0] = 0.f; acc[i][j][1] = 0.f; acc[i][j][2] = 0.f; acc[i][j][3] = 0.f;
    }

  const int lm = L & 15;    // fragment row within 16
  const int lq = L >> 4;    // quad

  // staging: sA = 1024 16B-chunks (4/thread), sB = 512 (2/thread).
  // chunk c: row = c>>2, c16 = c&3, source 16B-chunk = c16 ^ ((row>>1)&3).
  // (8B-half swizzle lives in the global arrays already -> DMA stays 16B-linear)
  const uint8_t* pA[4]; int dA[4];
#pragma unroll
  for (int j = 0; j < 4; ++j) {
    int c = tid + 256 * j;
    int r = c >> 2;
    int so = ((c & 3) ^ ((r >> 1) & 3)) * 16;
    pA[j] = A + (size_t)(m0 + r) * DD + so;
    dA[j] = c * 16;
  }
  const uint8_t* pB[2]; int dB[2];
#pragma unroll
  for (int j = 0; j < 2; ++j) {
    int c = tid + 256 * j;
    int r = c >> 2;
    int so = ((c & 3) ^ ((r >> 1) & 3)) * 16;
    pB[j] = Bt + (size_t)(n0 + r) * DD + so;
    dB[j] = c * 16;
  }

  auto stage = [&](int t, int p) {
#pragma unroll
    for (int j = 0; j < 4; ++j)
      __builtin_amdgcn_global_load_lds((const glb_u32_t*)(pA[j] + (size_t)t * BK),
                                       (lds_u32_t*)(&sA[p][0] + dA[j]), 16, 0, 0);
#pragma unroll
    for (int j = 0; j < 2; ++j)
      __builtin_amdgcn_global_load_lds((const glb_u32_t*)(pB[j] + (size_t)t * BK),
                                       (lds_u32_t*)(&sB[p][0] + dB[j]), 16, 0, 0);
  };

  // fragment read: logical 8B-chunk q = khalf*4 + lq of row; LDS byte =
  // row*64 + ((q>>1) ^ t2)*16 + ((q&1) ^ s3)*8, t2=(lm>>1)&3, s3=(lm>>3)&1.
  // Bank-pair = 8(lm&1) + 2*(chunk) + (halfbit): bijective over lm 0..15
  // per quarter-wave -> conflict-free ds_read_b64.
  const int t2 = (lm >> 1) & 3;
  const int s3 = (lm >> 3) & 1;
  const int raBase = (wr * 128 + lm) * BK;
  const int rbBase = (wc * 64 + lm) * BK;
  const int off0 = ((lq >> 1) ^ t2) * 16 + ((lq & 1) ^ s3) * 8;        // khalf 0
  const int off1 = ((2 + (lq >> 1)) ^ t2) * 16 + ((lq & 1) ^ s3) * 8;  // khalf 1

  // prologue: stage tiles 0,1 -> 12 loads outstanding per thread
  stage(0, 0);
  stage(1, 1);

  int cur = 0;
#pragma unroll 1
  for (int kt = 0; kt < DD / BK; ++kt) {
    // own tile-kt loads done (6 newest = tile kt+1 stay in flight);
    // all own ds_reads of tile kt-1 done -> safe for others to overwrite it.
    if (kt == DD / BK - 1)
      asm volatile("s_waitcnt vmcnt(0) lgkmcnt(0)" ::: "memory");
    else
      asm volatile("s_waitcnt vmcnt(6) lgkmcnt(0)" ::: "memory");
    __builtin_amdgcn_s_barrier();
    asm volatile("" ::: "memory");   // fence: no LDS ops hoisted above barrier

    if (kt < DD / BK - 2) {
      int stp = cur + 2; if (stp >= 3) stp -= 3;   // buffer of tile kt-1
      stage(kt + 2, stp);
    }

    const uint8_t* bufA = &sA[cur][0];
    const uint8_t* bufB = &sB[cur][0];

    __builtin_amdgcn_s_setprio(1);
    long long af[8], bf[4];
    // k-half 0
#pragma unroll
    for (int i = 0; i < 8; ++i)
      af[i] = *(const long long*)(bufA + raBase + i * 16 * BK + off0);
#pragma unroll
    for (int j = 0; j < 4; ++j)
      bf[j] = *(const long long*)(bufB + rbBase + j * 16 * BK + off0);
#pragma unroll
    for (int i = 0; i < 8; ++i)
#pragma unroll
      for (int j = 0; j < 4; ++j)
        acc[i][j] = __builtin_amdgcn_mfma_f32_16x16x32_fp8_fp8(af[i], bf[j], acc[i][j], 0, 0, 0);
    // k-half 1
#pragma unroll
    for (int i = 0; i < 8; ++i)
      af[i] = *(const long long*)(bufA + raBase + i * 16 * BK + off1);
#pragma unroll
    for (int j = 0; j < 4; ++j)
      bf[j] = *(const long long*)(bufB + rbBase + j * 16 * BK + off1);
#pragma unroll
    for (int i = 0; i < 8; ++i)
#pragma unroll
      for (int j = 0; j < 4; ++j)
        acc[i][j] = __builtin_amdgcn_mfma_f32_16x16x32_fp8_fp8(af[i], bf[j], acc[i][j], 0, 0, 0);
    __builtin_amdgcn_s_setprio(0);

    cur = (cur == 2) ? 0 : cur + 1;
  }

  // Epilogue: per-row top-2 over this wave's 64-col half (packed keys).
  // C/D layout (16x16x32): col = lane&15, row = (lane>>4)*4 + reg.
  const int col0 = wc * 64 + lm;
#pragma unroll
  for (int i = 0; i < 8; ++i) {
#pragma unroll
    for (int r = 0; r < 4; ++r) {
      uint32_t k1 = 0, k2 = 0;
#pragma unroll
      for (int j = 0; j < 4; ++j) {
        uint32_t kj = packkey(acc[i][j][r], col0 + j * 16);
        if (kj > k1) { k2 = k1; k1 = kj; }
        else k2 = max(k2, kj);
      }
#pragma unroll
      for (int msk = 1; msk < 16; msk <<= 1) {
        uint32_t o1 = (uint32_t)__shfl_xor((int)k1, msk, 64);
        uint32_t o2 = (uint32_t)__shfl_xor((int)k2, msk, 64);
        kmerge(k1, k2, o1, o2);
      }
      if (lm == 0) {
        int rl = wr * 128 + i * 16 + lq * 4 + r;
        mk[rl][wc] = make_uint2(k1, k2);
      }
    }
  }
  __syncthreads();
  {
    uint2 a = mk[tid][0], b = mk[tid][1];  // top-2 per 64-col half
    pk[(size_t)(m0 + tid) * NTILES + nx] = make_uint4(a.x, a.y, b.x, b.y);
  }
}

// ------- select: wave-per-row exact fp64 refinement + fused gather ----------
// One 64-lane wave per x-row; 4 rows per 256-thread block. No __syncthreads.
__global__ __launch_bounds__(256) void select_kernel(
    const float* __restrict__ x, const float* __restrict__ kw,
    const uint4* __restrict__ pk,
    const float* __restrict__ Gt, const float* __restrict__ G,
    float* __restrict__ out, float* __restrict__ out_w) {
  const int b = blockIdx.x * 4 + (threadIdx.x >> 6);
  const int L = threadIdx.x & 63;

  // x row: 16 floats/lane (4 x float4, coalesced)
  const float4* x4 = (const float4*)(x + (size_t)b * DD);
  float4 xv[4];
#pragma unroll
  for (int j = 0; j < 4; ++j) xv[j] = x4[L + 64 * j];

  // keys of tile L: top-2 of each 64-col half (k.x>=k.y, k.z>=k.w)
  uint4 kp = pk[(size_t)b * NTILES + L];

  // x2 in fp64 (xor-reduce -> all lanes hold total)
  double x2 = 0.0;
#pragma unroll
  for (int j = 0; j < 4; ++j)
    x2 += (double)xv[j].x * xv[j].x + (double)xv[j].y * xv[j].y +
          (double)xv[j].z * xv[j].z + (double)xv[j].w * xv[j].w;
#pragma unroll
  for (int msk = 1; msk < 64; msk <<= 1) x2 += __shfl_xor(x2, msk, 64);

  // global max key -> margin threshold (fp8 dot err rms ~0.05; 0.35 >= 5 sigma)
  uint32_t m = max(kp.x, kp.z);
#pragma unroll
  for (int msk = 1; msk < 64; msk <<= 1)
    m = max(m, (uint32_t)__shfl_xor((int)m, msk, 64));
  const uint32_t thrk = packkey(unpackval(m) - 0.35f, 0);

  unsigned long long cand[4];
  cand[0] = __ballot(kp.x >= thrk);
  cand[1] = __ballot(kp.y >= thrk);
  cand[2] = __ballot(kp.z >= thrk);
  cand[3] = __ballot(kp.w >= thrk);

  double best = 1e300;
  int bestc = 0x7fffffff;
#pragma unroll 1
  for (int pass = 0; pass < 4; ++pass) {
    unsigned long long bits = cand[pass];
    uint32_t mykey = (pass == 0) ? kp.x : (pass == 1) ? kp.y
                    : (pass == 2) ? kp.z : kp.w;
    while (bits) {
      int tt = __ffsll((long long)bits) - 1;   // candidate's tile = lane tt
      bits &= bits - 1;
      uint32_t kbt = (uint32_t)__shfl((int)mykey, tt, 64);
      int col = tt * 128 + (int)(kbt & 127u);
      const float4* k4 = (const float4*)(kw + (size_t)col * DD);
      double dot = 0.0, w2 = 0.0;
#pragma unroll
      for (int j = 0; j < 4; ++j) {
        float4 wv = k4[L + 64 * j];
        dot += (double)xv[j].x * wv.x + (double)xv[j].y * wv.y +
               (double)xv[j].z * wv.z + (double)xv[j].w * wv.w;
        w2 += (double)wv.x * wv.x + (double)wv.y * wv.y +
              (double)wv.z * wv.z + (double)wv.w * wv.w;
      }
#pragma unroll
      for (int msk = 1; msk < 64; msk <<= 1) {
        dot += __shfl_xor(dot, msk, 64);
        w2 += __shfl_xor(w2, msk, 64);
      }
      double sq = x2 + w2 - 2.0 * dot;   // identical on all lanes
      if (sq < best || (sq == best && col < bestc)) { best = sq; bestc = col; }
    }
  }

  if (L == 0) out_w[b] = (float)bestc;  // winners as fp32 (flat fp32 buffer)
  if (Gt != nullptr) {
    // coalesced gather: out[b,:] = Gt[bestc,:]  (wave-uniform bestc)
    const float4* gsrc = (const float4*)(Gt + (size_t)bestc * OO);
    float4* gdst = (float4*)(out + (size_t)b * OO);
#pragma unroll
    for (int j = 0; j < 4; ++j) {
      int q = L + 64 * j;
      if (q < OO / 4) gdst[q] = gsrc[q];
    }
  } else {
    // fallback: strided gather from G
#pragma unroll 1
    for (int j = 0; j < 16; ++j) {
      int o = L + 64 * j;
      if (o < OO) out[(size_t)b * OO + o] = G[(size_t)o * HH + bestc];
    }
  }
}

extern "C" void kernel_launch(void* const* d_in, const int* in_sizes, int n_in,
                              void* d_out, int out_size, void* d_ws, size_t ws_size,
                              hipStream_t stream) {
  const float* x  = (const float*)d_in[0];  // [4096][1024]
  const float* kw = (const float*)d_in[1];  // [8192][1024]
  const float* gw = (const float*)d_in[2];  // [1000][8192]
  float* out = (float*)d_out;               // [4096*1000] output ++ [4096] winners
  float* out_w = out + (size_t)BB * OO;

  const size_t MB = 1024 * 1024;
  char* ws = (char*)d_ws;
  uint8_t* xq = (uint8_t*)(ws);             // 4 MB
  uint8_t* kq = (uint8_t*)(ws + 4 * MB);    // 8 MB
  uint4*   pk = (uint4*)(ws + 12 * MB);     // 4 MB
  float*   Gt = (float*)(ws + 16 * MB);     // 32.77 MB
  const size_t need = 16 * MB + sizeof(float) * (size_t)HH * OO;
  float* GtArg = (ws_size >= need) ? Gt : nullptr;

  // 1) fp32 -> fp8 e4m3 (4 rows/block) + parallel G transpose tiles
  int cvt_blocks = (BB + HH) / 4 + (GtArg ? 2048 : 0);
  cvt_kernel<<<cvt_blocks, 256, 0, stream>>>(x, kw, xq, kq, gw, GtArg);

  // 2) fp8 MFMA GEMM + top-2 keys per 64-col half
  dim3 g(HH / BN, BB / BM);  // (64, 16)
  gemm_top2<<<g, 256, 0, stream>>>(xq, kq, pk);

  // 3) wave-per-row exact fp64 refinement -> winners, fused coalesced gather
  select_kernel<<<BB / 4, 256, 0, stream>>>(x, kw, pk, GtArg, gw, out, out_w);
}

// Round 4
// 198.889 us; speedup vs baseline: 1.1203x; 1.1203x over previous
//
#include <hip/hip_runtime.h>
#include <hip/hip_bf16.h>
#include <hip/hip_fp16.h>

// Problem: B=4096, D=1024, H=8192, O=1000
//   winners[b] = argmin_h ||x_b - k_h||  (== argmax dot, k rows unit-norm)
//   output[b,o] = G[o, winners[b]]
// Pipeline (3 dispatches; measured fixed replay overhead ~75 us):
//   1) cvt: fp32 -> fp8(e4m3) for x,kw (4 rows/block) + parallel G->Gt transpose
//   2) gemm_top2: MX-fp8 scores via mfma_scale_f32_32x32x64_f8f6f4 with UNIT
//      e8m0 scales (bit-identical to non-scaled fp8, ~2.3x issue rate; only
//      48 VGPR of fragments vs round-1's 128 -> occupancy preserved).
//      Block 256x128, BK=64, 4 waves, 128x64 wave-tile, acc[2][4] f32x16 AGPR.
//      TRIPLE-buffered LDS, counted vmcnt(6), ONE s_barrier per K-iter
//      (round-3 structure, proven race-free: STAGE(t+2) targets buf of t-1
//      whose reads drained at this iter's lgkmcnt(0)+barrier).
//      2-bit chunk swizzle (16B chunk ^ (row>>1)&3): ds_read_b128 lands 2-way
//      on banks = free (m136). SWAPPED operands mfma(B,A): each lane owns one
//      x-row's scores -> top-2 is a lane-local scan + one shfl_xor(32).
//   3) select: wave-per-row exact fp64 refinement (margin 0.35 >> fp8 dot err
//      ~0.05) + fused coalesced gather.

#define BB 4096
#define DD 1024
#define HH 8192
#define OO 1000

#define BM 256
#define BN 128
#define BK 64          // bytes == elements (fp8)
#define NTILES (HH / BN)   // 64
#define SA_TILE (BM * BK)  // 16384
#define SB_TILE (BN * BK)  // 8192

typedef _Float16 f16;
typedef float f32x16 __attribute__((ext_vector_type(16)));
typedef int v8i __attribute__((ext_vector_type(8)));
typedef int v4i __attribute__((ext_vector_type(4)));
union Frag { v8i v; v4i h[2]; };

typedef __attribute__((address_space(3))) uint32_t lds_u32_t;
typedef __attribute__((address_space(1))) uint32_t glb_u32_t;

// ---- packed key: monotone(float) with low 7 bits = tile-local column ----
__device__ __forceinline__ uint32_t packkey(float v, int col) {
  uint32_t u = __float_as_uint(v);
  uint32_t mask = (uint32_t)((int32_t)u >> 31) | 0x80000000u;
  u ^= mask;                       // monotone: bigger float -> bigger uint
  return (u & 0xFFFFFF80u) | (uint32_t)col;
}
__device__ __forceinline__ float unpackval(uint32_t k) {
  uint32_t u = k & 0xFFFFFF80u;
  uint32_t mask = (k & 0x80000000u) ? 0x80000000u : 0xFFFFFFFFu;
  return __uint_as_float(u ^ mask);
}
__device__ __forceinline__ void kmerge(uint32_t& k1, uint32_t& k2,
                                       uint32_t o1, uint32_t o2) {
  uint32_t mn = min(k1, o1);
  uint32_t alt = (k1 > o1) ? k2 : o2;
  k1 = max(k1, o1);
  k2 = max(mn, alt);
}

// -------- cvt: fp32 -> fp8 e4m3 (4 rows/block) + parallel transpose ---------
// blocks [0, 3072): 4 rows each of x (rows 0..BB-1) then kw (rows BB..BB+HH-1)
// blocks [3072, 3072+2048): 4 parallel 32x32 transpose tiles of G -> Gt
__global__ __launch_bounds__(256) void cvt_kernel(
    const float* __restrict__ x, const float* __restrict__ kw,
    uint8_t* __restrict__ xq, uint8_t* __restrict__ kq,
    const float* __restrict__ G, float* __restrict__ Gt) {
  const int tid = threadIdx.x;
  const int blk = blockIdx.x;
  __shared__ float tile[32][33];
  if (blk < (BB + HH) / 4) {
#pragma unroll
    for (int i = 0; i < 4; ++i) {
      int r = blk * 4 + i;
      const float* src = (r < BB) ? (x + (size_t)r * DD)
                                  : (kw + (size_t)(r - BB) * DD);
      uint8_t* dst = (r < BB) ? (xq + (size_t)r * DD)
                              : (kq + (size_t)(r - BB) * DD);
      float4 v = ((const float4*)src)[tid];
      int p = 0;
      p = __builtin_amdgcn_cvt_pk_fp8_f32(v.x, v.y, p, false);  // bytes 0,1
      p = __builtin_amdgcn_cvt_pk_fp8_f32(v.z, v.w, p, true);   // bytes 2,3
      ((int*)dst)[tid] = p;
    }
  } else {
    if (Gt == nullptr) return;
    const int tb = blk - (BB + HH) / 4;
    const int tx = tid & 31;
    const int ty = tid >> 5;  // 0..7
#pragma unroll 1
    for (int j4 = 0; j4 < 4; ++j4) {
      int tile_id = tb * 4 + j4;       // 0..8191
      int h0 = (tile_id >> 5) * 32;
      int o0 = (tile_id & 31) * 32;
      __syncthreads();
#pragma unroll
      for (int j = 0; j < 4; ++j) {
        int o = o0 + ty + j * 8;
        if (o < OO) tile[ty + j * 8][tx] = G[(size_t)o * HH + h0 + tx];
      }
      __syncthreads();
#pragma unroll
      for (int j = 0; j < 4; ++j) {
        int o = o0 + tx;
        int h = h0 + ty + j * 8;
        if (o < OO) Gt[(size_t)h * OO + o] = tile[tx][ty + j * 8];
      }
    }
  }
}

// ---------------- GEMM (MX-fp8 scores) + top-2 keys per half-tile -----------
// A = xq [B][D] fp8, Bt = kq [H][D] fp8 (NT). Block: 256x128 C-tile, BK=64,
// 16 K-iters, triple-buffered. Per iter per wave: 12 ds_read_b128 + 8 MFMA
// (32x32x64, swapped operands: D[h][x]); 6 gl_lds/thread.
__global__ __launch_bounds__(256, 2) void gemm_top2(
    const uint8_t* __restrict__ A, const uint8_t* __restrict__ Bt,
    uint4* __restrict__ pk) {
  __shared__ __align__(16) uint8_t sA[3][SA_TILE];  // 48 KB
  __shared__ __align__(16) uint8_t sB[3][SB_TILE];  // 24 KB
  __shared__ uint2 mk[BM][2];                       // 4 KB

  const int tid = threadIdx.x;
  const int w = tid >> 6;       // wave 0..3
  const int L = tid & 63;       // lane

  // XCD-aware bijective remap: grid 64x16 = 1024 blocks = 8 XCD * 128.
  // XCD c (= linear bid & 7) owns n-tiles [8c, 8c+8) across all m.
  const int bid = blockIdx.y * gridDim.x + blockIdx.x;
  const int c8 = bid & 7;
  const int tt = bid >> 3;           // 0..127
  const int nx = c8 * 8 + (tt & 7);  // 0..63
  const int my = tt >> 3;            // 0..15
  const int m0 = my * BM;
  const int n0 = nx * BN;

  const int wr = w >> 1;  // 0,1: row half (128 rows of x)
  const int wc = w & 1;   // 0,1: col half (64 cols of h)

  // swapped-operand accumulators: acc[i = h-tile 0..1][j = x-tile 0..3],
  // D[h][x] 32x32 each -> 128 AGPRs total.
  f32x16 acc[2][4];
#pragma unroll
  for (int i = 0; i < 2; ++i)
#pragma unroll
    for (int j = 0; j < 4; ++j)
#pragma unroll
      for (int q = 0; q < 16; ++q) acc[i][j][q] = 0.f;

  const int l31 = L & 31;   // row within a 32-row operand tile
  const int kh = L >> 5;    // which 32B K-chunk

  // staging: sA = 1024 16B-chunks (4/thread), sB = 512 (2/thread).
  // chunk c: row = c>>2, c16 = c&3, source 16B-chunk = c16 ^ ((row>>1)&3).
  const uint8_t* pA[4]; int dA[4];
#pragma unroll
  for (int j = 0; j < 4; ++j) {
    int c = tid + 256 * j;
    int r = c >> 2;
    int so = ((c & 3) ^ ((r >> 1) & 3)) * 16;
    pA[j] = A + (size_t)(m0 + r) * DD + so;
    dA[j] = c * 16;
  }
  const uint8_t* pB[2]; int dB[2];
#pragma unroll
  for (int j = 0; j < 2; ++j) {
    int c = tid + 256 * j;
    int r = c >> 2;
    int so = ((c & 3) ^ ((r >> 1) & 3)) * 16;
    pB[j] = Bt + (size_t)(n0 + r) * DD + so;
    dB[j] = c * 16;
  }

  auto stage = [&](int t, int p) {
#pragma unroll
    for (int j = 0; j < 4; ++j)
      __builtin_amdgcn_global_load_lds((const glb_u32_t*)(pA[j] + (size_t)t * BK),
                                       (lds_u32_t*)(&sA[p][0] + dA[j]), 16, 0, 0);
#pragma unroll
    for (int j = 0; j < 2; ++j)
      __builtin_amdgcn_global_load_lds((const glb_u32_t*)(pB[j] + (size_t)t * BK),
                                       (lds_u32_t*)(&sB[p][0] + dB[j]), 16, 0, 0);
  };

  // fragment read (A-layout rule, verified for 16x16x128 in a prior round:
  // row = lane & (M-1), 32B K-chunk = lane >> log2(M)): lane needs logical
  // 16B-chunks {2kh, 2kh+1} of its row; physical chunk = logical ^ t2,
  // t2 = (row>>1)&3 = (l31>>1)&3 (tile bases are multiples of 32).
  const int t2 = (l31 >> 1) & 3;
  const int off_lo = ((2 * kh) ^ t2) * 16;
  const int off_hi = ((2 * kh + 1) ^ t2) * 16;
  const int raBase = (wr * 128 + l31) * BK;
  const int rbBase = (wc * 64 + l31) * BK;

  // prologue: stage tiles 0,1 -> 12 loads outstanding per thread
  stage(0, 0);
  stage(1, 1);

  int cur = 0;
#pragma unroll 1
  for (int kt = 0; kt < DD / BK; ++kt) {
    // own tile-kt loads done (6 newest = tile kt+1 stay in flight);
    // all own ds_reads of tile kt-1 done -> safe for others to overwrite it.
    if (kt == DD / BK - 1)
      asm volatile("s_waitcnt vmcnt(0) lgkmcnt(0)" ::: "memory");
    else
      asm volatile("s_waitcnt vmcnt(6) lgkmcnt(0)" ::: "memory");
    __builtin_amdgcn_s_barrier();
    asm volatile("" ::: "memory");   // fence: no LDS ops hoisted above barrier

    if (kt < DD / BK - 2) {
      int stp = cur + 2; if (stp >= 3) stp -= 3;   // buffer of tile kt-1
      stage(kt + 2, stp);
    }

    const uint8_t* bufA = &sA[cur][0];
    const uint8_t* bufB = &sB[cur][0];

    __builtin_amdgcn_s_setprio(1);
    Frag af[4], bf[2];
#pragma unroll
    for (int j = 0; j < 4; ++j) {
      const uint8_t* base = bufA + raBase + j * 32 * BK;
      af[j].h[0] = *(const v4i*)(base + off_lo);
      af[j].h[1] = *(const v4i*)(base + off_hi);
    }
#pragma unroll
    for (int i = 0; i < 2; ++i) {
      const uint8_t* base = bufB + rbBase + i * 32 * BK;
      bf[i].h[0] = *(const v4i*)(base + off_lo);
      bf[i].h[1] = *(const v4i*)(base + off_hi);
    }
#pragma unroll
    for (int i = 0; i < 2; ++i)
#pragma unroll
      for (int j = 0; j < 4; ++j)
        acc[i][j] = __builtin_amdgcn_mfma_scale_f32_32x32x64_f8f6f4(
            bf[i].v, af[j].v, acc[i][j],
            0 /*A fmt fp8*/, 0 /*B fmt fp8*/,
            0, 0x7F7F7F7Fu /*unit e8m0*/, 0, 0x7F7F7F7Fu);
    __builtin_amdgcn_s_setprio(0);

    cur = (cur == 2) ? 0 : cur + 1;
  }

  // Epilogue (swapped D[h][x], 32x32 C-layout: x-col = lane&31,
  // h-row = (q&3) + 8*(q>>2) + 4*(lane>>5)): lane L owns x-row j*32+(L&31)
  // and 32 of its 64 h-scores (its kh half); local scan + one shfl_xor(32).
#pragma unroll
  for (int j = 0; j < 4; ++j) {
    uint32_t k1 = 0, k2 = 0;
#pragma unroll
    for (int i = 0; i < 2; ++i) {
#pragma unroll
      for (int q = 0; q < 16; ++q) {
        int hcol = wc * 64 + i * 32 + (q & 3) + 8 * (q >> 2) + 4 * kh;
        uint32_t kj = packkey(acc[i][j][q], hcol);
        if (kj > k1) { k2 = k1; k1 = kj; }
        else k2 = max(k2, kj);
      }
    }
    uint32_t o1 = (uint32_t)__shfl_xor((int)k1, 32, 64);
    uint32_t o2 = (uint32_t)__shfl_xor((int)k2, 32, 64);
    kmerge(k1, k2, o1, o2);
    if (kh == 0) mk[wr * 128 + j * 32 + l31][wc] = make_uint2(k1, k2);
  }
  __syncthreads();
  {
    uint2 a = mk[tid][0], b = mk[tid][1];  // top-2 per 64-col half
    pk[(size_t)(m0 + tid) * NTILES + nx] = make_uint4(a.x, a.y, b.x, b.y);
  }
}

// ------- select: wave-per-row exact fp64 refinement + fused gather ----------
// One 64-lane wave per x-row; 4 rows per 256-thread block. No __syncthreads.
__global__ __launch_bounds__(256) void select_kernel(
    const float* __restrict__ x, const float* __restrict__ kw,
    const uint4* __restrict__ pk,
    const float* __restrict__ Gt, const float* __restrict__ G,
    float* __restrict__ out, float* __restrict__ out_w) {
  const int b = blockIdx.x * 4 + (threadIdx.x >> 6);
  const int L = threadIdx.x & 63;

  // x row: 16 floats/lane (4 x float4, coalesced)
  const float4* x4 = (const float4*)(x + (size_t)b * DD);
  float4 xv[4];
#pragma unroll
  for (int j = 0; j < 4; ++j) xv[j] = x4[L + 64 * j];

  // keys of tile L: top-2 of each 64-col half (k.x>=k.y, k.z>=k.w)
  uint4 kp = pk[(size_t)b * NTILES + L];

  // x2 in fp64 (xor-reduce -> all lanes hold total)
  double x2 = 0.0;
#pragma unroll
  for (int j = 0; j < 4; ++j)
    x2 += (double)xv[j].x * xv[j].x + (double)xv[j].y * xv[j].y +
          (double)xv[j].z * xv[j].z + (double)xv[j].w * xv[j].w;
#pragma unroll
  for (int msk = 1; msk < 64; msk <<= 1) x2 += __shfl_xor(x2, msk, 64);

  // global max key -> margin threshold (fp8 dot err rms ~0.05; 0.35 >= 5 sigma)
  uint32_t m = max(kp.x, kp.z);
#pragma unroll
  for (int msk = 1; msk < 64; msk <<= 1)
    m = max(m, (uint32_t)__shfl_xor((int)m, msk, 64));
  const uint32_t thrk = packkey(unpackval(m) - 0.35f, 0);

  unsigned long long cand[4];
  cand[0] = __ballot(kp.x >= thrk);
  cand[1] = __ballot(kp.y >= thrk);
  cand[2] = __ballot(kp.z >= thrk);
  cand[3] = __ballot(kp.w >= thrk);

  double best = 1e300;
  int bestc = 0x7fffffff;
#pragma unroll 1
  for (int pass = 0; pass < 4; ++pass) {
    unsigned long long bits = cand[pass];
    uint32_t mykey = (pass == 0) ? kp.x : (pass == 1) ? kp.y
                    : (pass == 2) ? kp.z : kp.w;
    while (bits) {
      int tt = __ffsll((long long)bits) - 1;   // candidate's tile = lane tt
      bits &= bits - 1;
      uint32_t kbt = (uint32_t)__shfl((int)mykey, tt, 64);
      int col = tt * 128 + (int)(kbt & 127u);
      const float4* k4 = (const float4*)(kw + (size_t)col * DD);
      double dot = 0.0, w2 = 0.0;
#pragma unroll
      for (int j = 0; j < 4; ++j) {
        float4 wv = k4[L + 64 * j];
        dot += (double)xv[j].x * wv.x + (double)xv[j].y * wv.y +
               (double)xv[j].z * wv.z + (double)xv[j].w * wv.w;
        w2 += (double)wv.x * wv.x + (double)wv.y * wv.y +
              (double)wv.z * wv.z + (double)wv.w * wv.w;
      }
#pragma unroll
      for (int msk = 1; msk < 64; msk <<= 1) {
        dot += __shfl_xor(dot, msk, 64);
        w2 += __shfl_xor(w2, msk, 64);
      }
      double sq = x2 + w2 - 2.0 * dot;   // identical on all lanes
      if (sq < best || (sq == best && col < bestc)) { best = sq; bestc = col; }
    }
  }

  if (L == 0) out_w[b] = (float)bestc;  // winners as fp32 (flat fp32 buffer)
  if (Gt != nullptr) {
    // coalesced gather: out[b,:] = Gt[bestc,:]  (wave-uniform bestc)
    const float4* gsrc = (const float4*)(Gt + (size_t)bestc * OO);
    float4* gdst = (float4*)(out + (size_t)b * OO);
#pragma unroll
    for (int j = 0; j < 4; ++j) {
      int q = L + 64 * j;
      if (q < OO / 4) gdst[q] = gsrc[q];
    }
  } else {
    // fallback: strided gather from G
#pragma unroll 1
    for (int j = 0; j < 16; ++j) {
      int o = L + 64 * j;
      if (o < OO) out[(size_t)b * OO + o] = G[(size_t)o * HH + bestc];
    }
  }
}

extern "C" void kernel_launch(void* const* d_in, const int* in_sizes, int n_in,
                              void* d_out, int out_size, void* d_ws, size_t ws_size,
                              hipStream_t stream) {
  const float* x  = (const float*)d_in[0];  // [4096][1024]
  const float* kw = (const float*)d_in[1];  // [8192][1024]
  const float* gw = (const float*)d_in[2];  // [1000][8192]
  float* out = (float*)d_out;               // [4096*1000] output ++ [4096] winners
  float* out_w = out + (size_t)BB * OO;

  const size_t MB = 1024 * 1024;
  char* ws = (char*)d_ws;
  uint8_t* xq = (uint8_t*)(ws);             // 4 MB
  uint8_t* kq = (uint8_t*)(ws + 4 * MB);    // 8 MB
  uint4*   pk = (uint4*)(ws + 12 * MB);     // 4 MB
  float*   Gt = (float*)(ws + 16 * MB);     // 32.77 MB
  const size_t need = 16 * MB + sizeof(float) * (size_t)HH * OO;
  float* GtArg = (ws_size >= need) ? Gt : nullptr;

  // 1) fp32 -> fp8 e4m3 (4 rows/block) + parallel G transpose tiles
  int cvt_blocks = (BB + HH) / 4 + (GtArg ? 2048 : 0);
  cvt_kernel<<<cvt_blocks, 256, 0, stream>>>(x, kw, xq, kq, gw, GtArg);

  // 2) MX-fp8 MFMA GEMM + top-2 keys per 64-col half
  dim3 g(HH / BN, BB / BM);  // (64, 16)
  gemm_top2<<<g, 256, 0, stream>>>(xq, kq, pk);

  // 3) wave-per-row exact fp64 refinement -> winners, fused coalesced gather
  select_kernel<<<BB / 4, 256, 0, stream>>>(x, kw, pk, GtArg, gw, out, out_w);
}